// Round 13
// baseline (78.960 us; speedup 1.0000x reference)
//
#include <hip/hip_runtime.h>

// Coords are all {0,1}; STRIDES is a mixed-radix positional encoding, so each
// row maps bijectively to a 16-bit pattern. Whole op = 65536-bin float
// histogram + gather.
//
// R0-R2: global fp32 atomicAdd executes at the memory-side coherence point
// regardless of scope (~19G ops/s cap) -> no global atomics anywhere.
// R4: LDS-partitioned build (8 parts x 8192 bins, 1024-thr blocks).
// R6/R9/R10: int4-per-thread + 4-lane __shfl_xor nibble combine; 8 named
// in-flight loads per thread (VGPR 16->32).
// R11/R12: (1) NON-TEMPORAL loads for the once-read 266MB coord streams
// (bypass L3 allocation; keeps pat/part_hists/hist resident); (2) NSLICES
// 64->32 (halves part_hists traffic); (3) nt-store for out (via ext_vector
// type — __builtin_nontemporal_store rejects HIP_vector_type float4).
// NOTE: profiled per-dispatch dur_us is inflated by counter collection —
// trust end-to-end dur_us and traffic ratios only.

#define REL_W 16
#define NBINS 65536
#define NPART 8
#define BPP 8192        // bins per partition (32 KB as floats)
#define NSLICES 32
#define BUILD_BLK 1024
#define BLK 256
#define EUNROLL 8       // int4s per thread in extract

typedef unsigned short ushort8_t __attribute__((ext_vector_type(8)));
typedef int   int4v   __attribute__((ext_vector_type(4)));
typedef float float4v __attribute__((ext_vector_type(4)));

__device__ __forceinline__ unsigned pattern_of(const int* __restrict__ row) {
    const int4* p = reinterpret_cast<const int4*>(row);
    unsigned pat = 0;
#pragma unroll
    for (int k = 0; k < 4; ++k) {
        int4 v = p[k];
        pat |= (unsigned)(v.x & 1) << (k * 4 + 0);
        pat |= (unsigned)(v.y & 1) << (k * 4 + 1);
        pat |= (unsigned)(v.z & 1) << (k * 4 + 2);
        pat |= (unsigned)(v.w & 1) << (k * 4 + 3);
    }
    return pat;
}

__device__ __forceinline__ unsigned nibble_of(int4v v) {
    return (unsigned)(v.x & 1) | ((unsigned)(v.y & 1) << 1) |
           ((unsigned)(v.z & 1) << 2) | ((unsigned)(v.w & 1) << 3);
}

__device__ __forceinline__ int4v nt_load(const int4v* __restrict__ p) {
    return __builtin_nontemporal_load(p);
}

// combine 4-lane nibbles into a u16 pattern; lane k==0 of each group stores
__device__ __forceinline__ void emit_pat(unsigned g, unsigned nib, unsigned k, unsigned sh,
                                         unsigned short* __restrict__ dst) {
    unsigned val = nib << sh;
    val |= __shfl_xor(val, 1);
    val |= __shfl_xor(val, 2);
    if (k == 0) dst[g >> 2] = (unsigned short)val;
}

// 8 int4s per thread, spaced BLK apart (wave loads contiguous: 1KB/instr).
// Source select is block-uniform except the (at most one) boundary block.
__global__ __launch_bounds__(BLK) void extract_both8(const int* __restrict__ stored,
                                                     const int* __restrict__ queries,
                                                     unsigned short* __restrict__ pat_s,
                                                     unsigned short* __restrict__ pat_q,
                                                     int ns, int nq) {
    const int4v* sv = reinterpret_cast<const int4v*>(stored);
    const int4v* qv = reinterpret_cast<const int4v*>(queries);
    int ns4  = ns * 4;
    int tot4 = (ns + nq) * 4;
    int blk_lo = blockIdx.x * (BLK * EUNROLL);
    int blk_hi = blk_lo + BLK * EUNROLL;           // exclusive
    int base   = blk_lo + (int)threadIdx.x;
    unsigned k  = (unsigned)threadIdx.x & 3;       // group index (stride BLK keeps it)
    unsigned sh = 4 * k;

    if (blk_hi <= ns4) {
        int4v v0 = nt_load(sv + base + 0 * BLK), v1 = nt_load(sv + base + 1 * BLK);
        int4v v2 = nt_load(sv + base + 2 * BLK), v3 = nt_load(sv + base + 3 * BLK);
        int4v v4 = nt_load(sv + base + 4 * BLK), v5 = nt_load(sv + base + 5 * BLK);
        int4v v6 = nt_load(sv + base + 6 * BLK), v7 = nt_load(sv + base + 7 * BLK);
        emit_pat(base + 0 * BLK, nibble_of(v0), k, sh, pat_s);
        emit_pat(base + 1 * BLK, nibble_of(v1), k, sh, pat_s);
        emit_pat(base + 2 * BLK, nibble_of(v2), k, sh, pat_s);
        emit_pat(base + 3 * BLK, nibble_of(v3), k, sh, pat_s);
        emit_pat(base + 4 * BLK, nibble_of(v4), k, sh, pat_s);
        emit_pat(base + 5 * BLK, nibble_of(v5), k, sh, pat_s);
        emit_pat(base + 6 * BLK, nibble_of(v6), k, sh, pat_s);
        emit_pat(base + 7 * BLK, nibble_of(v7), k, sh, pat_s);
    } else if (blk_lo >= ns4 && blk_hi <= tot4) {
        int b = base - ns4;
        int4v v0 = nt_load(qv + b + 0 * BLK), v1 = nt_load(qv + b + 1 * BLK);
        int4v v2 = nt_load(qv + b + 2 * BLK), v3 = nt_load(qv + b + 3 * BLK);
        int4v v4 = nt_load(qv + b + 4 * BLK), v5 = nt_load(qv + b + 5 * BLK);
        int4v v6 = nt_load(qv + b + 6 * BLK), v7 = nt_load(qv + b + 7 * BLK);
        emit_pat(b + 0 * BLK, nibble_of(v0), k, sh, pat_q);
        emit_pat(b + 1 * BLK, nibble_of(v1), k, sh, pat_q);
        emit_pat(b + 2 * BLK, nibble_of(v2), k, sh, pat_q);
        emit_pat(b + 3 * BLK, nibble_of(v3), k, sh, pat_q);
        emit_pat(b + 4 * BLK, nibble_of(v4), k, sh, pat_q);
        emit_pat(b + 5 * BLK, nibble_of(v5), k, sh, pat_q);
        emit_pat(b + 6 * BLK, nibble_of(v6), k, sh, pat_q);
        emit_pat(b + 7 * BLK, nibble_of(v7), k, sh, pat_q);
    } else {
        // boundary / tail block: per-element guarded path
#pragma unroll
        for (int j = 0; j < EUNROLL; ++j) {
            int g = base + j * BLK;
            if (g < tot4) {
                int4v v = (g < ns4) ? nt_load(sv + g) : nt_load(qv + (g - ns4));
                unsigned val = nibble_of(v) << sh;
                val |= __shfl_xor(val, 1);
                val |= __shfl_xor(val, 2);
                if (k == 0) {
                    if (g < ns4) pat_s[g >> 2] = (unsigned short)val;
                    else         pat_q[(g - ns4) >> 2] = (unsigned short)val;
                }
            }
        }
    }
}

__global__ __launch_bounds__(BUILD_BLK) void build_parts(const unsigned short* __restrict__ pats,
                                                         const float* __restrict__ vals,
                                                         float* __restrict__ part_hists, int n) {
    __shared__ float lh[BPP];
    unsigned part  = blockIdx.x / NSLICES;
    unsigned slice = blockIdx.x % NSLICES;
    for (int b = threadIdx.x; b < BPP; b += BUILD_BLK) lh[b] = 0.0f;
    __syncthreads();

    int per = ((n + NSLICES - 1) / NSLICES + 7) & ~7;
    int lo = (int)slice * per;
    int hi = min(n, lo + per);
    if (lo < hi) {
        int m = hi - lo;
        int nvec = m >> 3;
        const ushort8_t* pv = reinterpret_cast<const ushort8_t*>(pats + lo);
        const float4*    vv = reinterpret_cast<const float4*>(vals + lo);
        for (int v = threadIdx.x; v < nvec; v += BUILD_BLK) {
            ushort8_t p8 = pv[v];
            float4 v0 = vv[2 * v];
            float4 v1 = vv[2 * v + 1];
            float vsc[8] = {v0.x, v0.y, v0.z, v0.w, v1.x, v1.y, v1.z, v1.w};
#pragma unroll
            for (int kk = 0; kk < 8; ++kk) {
                unsigned pat = p8[kk];
                if ((pat >> 13) == part)
                    atomicAdd(&lh[pat & (BPP - 1)], vsc[kk]);   // ds_add_f32, on-CU
            }
        }
        for (int i = lo + (nvec << 3) + (int)threadIdx.x; i < hi; i += BUILD_BLK) {
            unsigned pat = pats[i];
            if ((pat >> 13) == part)
                atomicAdd(&lh[pat & (BPP - 1)], vals[i]);
        }
    }
    __syncthreads();
    float* dst = part_hists + (size_t)blockIdx.x * BPP;
    for (int b = threadIdx.x; b < BPP; b += BUILD_BLK) dst[b] = lh[b];
}

__global__ void reduce_parts(const float* __restrict__ part_hists, float* __restrict__ final_h) {
    int g = blockIdx.x * blockDim.x + threadIdx.x;   // bin 0..65535
    unsigned part = (unsigned)g >> 13;
    unsigned b = (unsigned)g & (BPP - 1);
    const float* src = part_hists + ((size_t)part * NSLICES) * BPP + b;
    float s = 0.0f;
#pragma unroll 8
    for (int sl = 0; sl < NSLICES; ++sl) s += src[(size_t)sl * BPP];
    final_h[g] = s;
}

// tiny final gather: 4 queries per thread via ushort4 + float4v nt store
__global__ __launch_bounds__(BLK) void gather_pat(const unsigned short* __restrict__ pq,
                                                  const float* __restrict__ h,
                                                  float* __restrict__ out, int n) {
    int t = blockIdx.x * blockDim.x + threadIdx.x;
    int base = t * 4;
    if (base + 4 <= n) {
        ushort4 p4 = *reinterpret_cast<const ushort4*>(pq + base);
        float4v o;
        o.x = h[p4.x]; o.y = h[p4.y]; o.z = h[p4.z]; o.w = h[p4.w];
        __builtin_nontemporal_store(o, reinterpret_cast<float4v*>(out + base));
    } else {
        for (int i = base; i < n; ++i) out[i] = h[pq[i]];
    }
}

// ---- fallback (R0 path) if workspace too small ----
__global__ void build_hist_dev(const int* __restrict__ coords, const float* __restrict__ vals,
                               float* __restrict__ hist, int n) {
    int i = blockIdx.x * blockDim.x + threadIdx.x;
    if (i >= n) return;
    atomicAdd(&hist[pattern_of(coords + (size_t)i * REL_W)], vals[i]);
}
__global__ void gather_coord(const int* __restrict__ queries, const float* __restrict__ hist,
                             float* __restrict__ out, int n) {
    int i = blockIdx.x * blockDim.x + threadIdx.x;
    if (i >= n) return;
    out[i] = hist[pattern_of(queries + (size_t)i * REL_W)];
}

static inline size_t align_up(size_t x, size_t a) { return (x + a - 1) & ~(a - 1); }

extern "C" void kernel_launch(void* const* d_in, const int* in_sizes, int n_in,
                              void* d_out, int out_size, void* d_ws, size_t ws_size,
                              hipStream_t stream) {
    const int*   stored  = (const int*)d_in[0];   // [N_store, 16] int32
    const int*   queries = (const int*)d_in[1];   // [N_query, 16] int32
    const float* vals    = (const float*)d_in[2]; // [N_store] f32
    float*       out     = (float*)d_out;         // [N_query] f32

    int n_store = in_sizes[0] / REL_W;
    int n_query = in_sizes[1] / REL_W;

    // workspace layout
    size_t off_pat_s = 0;
    size_t off_pat_q = align_up(off_pat_s + (size_t)n_store * 2, 256);
    size_t off_hists = align_up(off_pat_q + (size_t)n_query * 2, 256);
    size_t off_final = off_hists + (size_t)NPART * NSLICES * BPP * sizeof(float);
    size_t need      = off_final + (size_t)NBINS * sizeof(float);

    if (ws_size >= need) {
        unsigned short* pat_s = (unsigned short*)((char*)d_ws + off_pat_s);
        unsigned short* pat_q = (unsigned short*)((char*)d_ws + off_pat_q);
        float* part_hists     = (float*)((char*)d_ws + off_hists);
        float* final_h        = (float*)((char*)d_ws + off_final);

        int tot4    = (n_store + n_query) * 4;
        int eblocks = (tot4 + BLK * EUNROLL - 1) / (BLK * EUNROLL);
        int gblocks = (n_query + BLK * 4 - 1) / (BLK * 4);
        extract_both8<<<eblocks, BLK, 0, stream>>>(stored, queries, pat_s, pat_q, n_store, n_query);
        build_parts<<<NPART * NSLICES, BUILD_BLK, 0, stream>>>(pat_s, vals, part_hists, n_store);
        reduce_parts<<<NBINS / BLK, BLK, 0, stream>>>(part_hists, final_h);
        gather_pat<<<gblocks, BLK, 0, stream>>>(pat_q, final_h, out, n_query);
    } else {
        float* hist = (float*)d_ws;
        hipMemsetAsync(d_ws, 0, NBINS * sizeof(float), stream);
        build_hist_dev<<<(n_store + BLK - 1) / BLK, BLK, 0, stream>>>(stored, vals, hist, n_store);
        gather_coord<<<(n_query + BLK - 1) / BLK, BLK, 0, stream>>>(queries, hist, out, n_query);
    }
}

// Round 14
// 78.229 us; speedup vs baseline: 1.0093x; 1.0093x over previous
//
#include <hip/hip_runtime.h>

// Coords are all {0,1}; STRIDES is a mixed-radix positional encoding, so each
// row maps bijectively to a 16-bit pattern. Whole op = 65536-bin float
// histogram + gather.
//
// R0-R2: global fp32 atomicAdd executes at the memory-side coherence point
// regardless of scope (~19G ops/s cap) -> no global atomics anywhere.
// R4: LDS-partitioned build (8 parts x 8192 bins, 1024-thr blocks).
// R6: 4-lane __shfl_xor nibble combine (coalesced 16B/lane reads).
// R10/R12 lesson: every reg-staged extract variant caps at the same read rate
// because in-flight loads are VGPR-limited (compiler keeps ~2-4 live).
// R13: async DMA staging via __builtin_amdgcn_global_load_lds - outstanding
// bytes live in the vmcnt queue, not VGPRs. 2x32KB LDS dbuf, 8 DMA/wave per
// chunk, counted vmcnt(16/8/0) + raw s_barrier (never drain next chunk).

#define REL_W 16
#define NBINS 65536
#define NPART 8
#define BPP 8192        // bins per partition (32 KB as floats)
#define NSLICES 32
#define BUILD_BLK 1024
#define BLK 256
#define EX_BLK 256
#define CHUNK 2048      // int4s per buffer (32 KB)

typedef unsigned short ushort8_t __attribute__((ext_vector_type(8)));
typedef int   int4v   __attribute__((ext_vector_type(4)));

__device__ __forceinline__ unsigned pattern_of(const int* __restrict__ row) {
    const int4* p = reinterpret_cast<const int4*>(row);
    unsigned pat = 0;
#pragma unroll
    for (int k = 0; k < 4; ++k) {
        int4 v = p[k];
        pat |= (unsigned)(v.x & 1) << (k * 4 + 0);
        pat |= (unsigned)(v.y & 1) << (k * 4 + 1);
        pat |= (unsigned)(v.z & 1) << (k * 4 + 2);
        pat |= (unsigned)(v.w & 1) << (k * 4 + 3);
    }
    return pat;
}

__device__ __forceinline__ unsigned nibble_of(int4v v) {
    return (unsigned)(v.x & 1) | ((unsigned)(v.y & 1) << 1) |
           ((unsigned)(v.z & 1) << 2) | ((unsigned)(v.w & 1) << 3);
}

// DMA-staged extraction of both coord arrays -> u16 patterns.
__global__ __launch_bounds__(EX_BLK) void extract_dma(const int* __restrict__ stored,
                                                      const int* __restrict__ queries,
                                                      unsigned short* __restrict__ pat_s,
                                                      unsigned short* __restrict__ pat_q,
                                                      long ns4, long tot4, int iters) {
    __shared__ int4v buf[2][CHUNK];                 // 64 KB
    const int4v* sv = reinterpret_cast<const int4v*>(stored);
    const int4v* qv = reinterpret_cast<const int4v*>(queries);
    const int t = threadIdx.x;
    const unsigned k = (unsigned)t & 3, sh = 4 * k;
    const long g0 = (long)blockIdx.x * CHUNK * iters;

#define CHUNK_LO(it) (g0 + (long)(it) * CHUNK)
#define IS_VALID(it) ((it) < iters && CHUNK_LO(it) < tot4)
#define IS_SIMPLE(it) ((it) < iters && CHUNK_LO(it) + CHUNK <= tot4 && \
                       !(CHUNK_LO(it) < ns4 && CHUNK_LO(it) + CHUNK > ns4))

#define ISSUE(b, it) do {                                                         \
        long _c = CHUNK_LO(it);                                                   \
        const int4v* _src = (_c < ns4) ? (sv + _c) : (qv + (_c - ns4));           \
        _Pragma("unroll")                                                         \
        for (int _s = 0; _s < 8; ++_s) {                                          \
            int _idx = _s * EX_BLK + t;                                           \
            __builtin_amdgcn_global_load_lds(                                     \
                (const __attribute__((address_space(1))) void*)(_src + _idx),     \
                (__attribute__((address_space(3))) void*)(&buf[b][_idx]),         \
                16, 0, 0);                                                        \
        }                                                                         \
    } while (0)

    bool prev_store = false;
    if (IS_SIMPLE(0)) ISSUE(0, 0);

    for (int it = 0; IS_VALID(it); ++it) {
        bool cur_simple = IS_SIMPLE(it);
        bool nxt_issue  = IS_SIMPLE(it + 1);
        if (nxt_issue) ISSUE((it + 1) & 1, it + 1);

        int X = (nxt_issue ? 8 : 0) + (prev_store ? 8 : 0);
        if (X == 16)     asm volatile("s_waitcnt vmcnt(16)" ::: "memory");
        else if (X == 8) asm volatile("s_waitcnt vmcnt(8)" ::: "memory");
        else             asm volatile("s_waitcnt vmcnt(0)" ::: "memory");
        __builtin_amdgcn_s_barrier();
        asm volatile("" ::: "memory");

        long c = CHUNK_LO(it);
        if (cur_simple) {
            bool isq = (c >= ns4);
            unsigned short* __restrict__ dst = isq ? pat_q : pat_s;
            long cc = isq ? (c - ns4) : c;
#pragma unroll
            for (int s = 0; s < 8; ++s) {
                int idx = s * EX_BLK + t;
                int4v v = buf[it & 1][idx];
                unsigned val = nibble_of(v) << sh;
                val |= __shfl_xor(val, 1);
                val |= __shfl_xor(val, 2);
                if (k == 0) dst[(cc + idx) >> 2] = (unsigned short)val;
            }
            prev_store = true;
        } else {
            // boundary/tail chunk: direct guarded path (rare)
            for (int s = 0; s < 8; ++s) {
                long g = c + s * EX_BLK + t;
                if (g < tot4) {
                    int4v v = (g < ns4) ? sv[g] : qv[g - ns4];
                    unsigned val = nibble_of(v) << sh;
                    val |= __shfl_xor(val, 1);
                    val |= __shfl_xor(val, 2);
                    if (k == 0) {
                        if (g < ns4) pat_s[g >> 2] = (unsigned short)val;
                        else         pat_q[(g - ns4) >> 2] = (unsigned short)val;
                    }
                }
            }
            prev_store = false;     // unknown vmem count -> conservative waits
        }
        asm volatile("" ::: "memory");
        __builtin_amdgcn_s_barrier();
    }
#undef ISSUE
#undef IS_SIMPLE
#undef IS_VALID
#undef CHUNK_LO
}

__global__ __launch_bounds__(BUILD_BLK) void build_parts(const unsigned short* __restrict__ pats,
                                                         const float* __restrict__ vals,
                                                         float* __restrict__ part_hists, int n) {
    __shared__ float lh[BPP];
    unsigned part  = blockIdx.x / NSLICES;
    unsigned slice = blockIdx.x % NSLICES;
    for (int b = threadIdx.x; b < BPP; b += BUILD_BLK) lh[b] = 0.0f;
    __syncthreads();

    int per = ((n + NSLICES - 1) / NSLICES + 7) & ~7;
    int lo = (int)slice * per;
    int hi = min(n, lo + per);
    if (lo < hi) {
        int m = hi - lo;
        int nvec = m >> 3;
        const ushort8_t* pv = reinterpret_cast<const ushort8_t*>(pats + lo);
        const float4*    vv = reinterpret_cast<const float4*>(vals + lo);
        for (int v = threadIdx.x; v < nvec; v += BUILD_BLK) {
            ushort8_t p8 = pv[v];
            float4 v0 = vv[2 * v];
            float4 v1 = vv[2 * v + 1];
            float vsc[8] = {v0.x, v0.y, v0.z, v0.w, v1.x, v1.y, v1.z, v1.w};
#pragma unroll
            for (int kk = 0; kk < 8; ++kk) {
                unsigned pat = p8[kk];
                if ((pat >> 13) == part)
                    atomicAdd(&lh[pat & (BPP - 1)], vsc[kk]);   // ds_add_f32, on-CU
            }
        }
        for (int i = lo + (nvec << 3) + (int)threadIdx.x; i < hi; i += BUILD_BLK) {
            unsigned pat = pats[i];
            if ((pat >> 13) == part)
                atomicAdd(&lh[pat & (BPP - 1)], vals[i]);
        }
    }
    __syncthreads();
    float* dst = part_hists + (size_t)blockIdx.x * BPP;
    for (int b = threadIdx.x; b < BPP; b += BUILD_BLK) dst[b] = lh[b];
}

__global__ void reduce_parts(const float* __restrict__ part_hists, float* __restrict__ final_h) {
    int g = blockIdx.x * blockDim.x + threadIdx.x;   // bin 0..65535
    unsigned part = (unsigned)g >> 13;
    unsigned b = (unsigned)g & (BPP - 1);
    const float* src = part_hists + ((size_t)part * NSLICES) * BPP + b;
    float s = 0.0f;
#pragma unroll 8
    for (int sl = 0; sl < NSLICES; ++sl) s += src[(size_t)sl * BPP];
    final_h[g] = s;
}

// tiny final gather: 4 queries per thread via ushort4 + float4 store
__global__ __launch_bounds__(BLK) void gather_pat(const unsigned short* __restrict__ pq,
                                                  const float* __restrict__ h,
                                                  float* __restrict__ out, int n) {
    int t = blockIdx.x * blockDim.x + threadIdx.x;
    int base = t * 4;
    if (base + 4 <= n) {
        ushort4 p4 = *reinterpret_cast<const ushort4*>(pq + base);
        float4 o;
        o.x = h[p4.x]; o.y = h[p4.y]; o.z = h[p4.z]; o.w = h[p4.w];
        *reinterpret_cast<float4*>(out + base) = o;
    } else {
        for (int i = base; i < n; ++i) out[i] = h[pq[i]];
    }
}

// ---- fallback (R0 path) if workspace too small ----
__global__ void build_hist_dev(const int* __restrict__ coords, const float* __restrict__ vals,
                               float* __restrict__ hist, int n) {
    int i = blockIdx.x * blockDim.x + threadIdx.x;
    if (i >= n) return;
    atomicAdd(&hist[pattern_of(coords + (size_t)i * REL_W)], vals[i]);
}
__global__ void gather_coord(const int* __restrict__ queries, const float* __restrict__ hist,
                             float* __restrict__ out, int n) {
    int i = blockIdx.x * blockDim.x + threadIdx.x;
    if (i >= n) return;
    out[i] = hist[pattern_of(queries + (size_t)i * REL_W)];
}

static inline size_t align_up(size_t x, size_t a) { return (x + a - 1) & ~(a - 1); }

extern "C" void kernel_launch(void* const* d_in, const int* in_sizes, int n_in,
                              void* d_out, int out_size, void* d_ws, size_t ws_size,
                              hipStream_t stream) {
    const int*   stored  = (const int*)d_in[0];   // [N_store, 16] int32
    const int*   queries = (const int*)d_in[1];   // [N_query, 16] int32
    const float* vals    = (const float*)d_in[2]; // [N_store] f32
    float*       out     = (float*)d_out;         // [N_query] f32

    int n_store = in_sizes[0] / REL_W;
    int n_query = in_sizes[1] / REL_W;

    // workspace layout
    size_t off_pat_s = 0;
    size_t off_pat_q = align_up(off_pat_s + (size_t)n_store * 2, 256);
    size_t off_hists = align_up(off_pat_q + (size_t)n_query * 2, 256);
    size_t off_final = off_hists + (size_t)NPART * NSLICES * BPP * sizeof(float);
    size_t need      = off_final + (size_t)NBINS * sizeof(float);

    if (ws_size >= need) {
        unsigned short* pat_s = (unsigned short*)((char*)d_ws + off_pat_s);
        unsigned short* pat_q = (unsigned short*)((char*)d_ws + off_pat_q);
        float* part_hists     = (float*)((char*)d_ws + off_hists);
        float* final_h        = (float*)((char*)d_ws + off_final);

        long ns4  = (long)n_store * 4;
        long tot4 = (long)(n_store + n_query) * 4;
        int chunks = (int)((tot4 + CHUNK - 1) / CHUNK);
        int iters  = (chunks + 511) / 512;
        int egrid  = (chunks + iters - 1) / iters;
        int gblocks = (n_query + BLK * 4 - 1) / (BLK * 4);

        extract_dma<<<egrid, EX_BLK, 0, stream>>>(stored, queries, pat_s, pat_q, ns4, tot4, iters);
        build_parts<<<NPART * NSLICES, BUILD_BLK, 0, stream>>>(pat_s, vals, part_hists, n_store);
        reduce_parts<<<NBINS / BLK, BLK, 0, stream>>>(part_hists, final_h);
        gather_pat<<<gblocks, BLK, 0, stream>>>(pat_q, final_h, out, n_query);
    } else {
        float* hist = (float*)d_ws;
        hipMemsetAsync(d_ws, 0, NBINS * sizeof(float), stream);
        build_hist_dev<<<(n_store + BLK - 1) / BLK, BLK, 0, stream>>>(stored, vals, hist, n_store);
        gather_coord<<<(n_query + BLK - 1) / BLK, BLK, 0, stream>>>(queries, hist, out, n_query);
    }
}